// Round 2
// baseline (323.580 us; speedup 1.0000x reference)
//
#include <hip/hip_runtime.h>
#include <hip/hip_bf16.h>
#include <math.h>

#define N_PTS 32768
#define IN_F  256
#define NUM_CAT 16
#define CF    4096
#define NSEG  6
#define OUTK  50
#define BN_EPS 1e-5f

// ---- ws layout (float offsets). Fixed region first, K-split partials after.
#define OFF_G     0u         // 256*256
#define OFF_FBAR  65536u     // 256
#define OFF_SCALE 65792u     // 4096
#define OFF_SHIFT 69888u     // 4096
#define OFF_INT   73984u     // int region: 67 + 32768 ints = 32835 -> ends 106819
#define OFF_GP    106832u    // Gram partials: 10 tiles * nchunk * 64*64 floats
// col-sum partials at OFF_GP + 40960*nchunk (nchunk*256 floats)
// int offsets (in ints, relative to OFF_INT)
#define IO_COUNTS 0
#define IO_CATOFF 16
#define IO_TILEST 33
#define IO_NTILES 50
#define IO_CURSOR 51
#define IO_ORDER  67
// total bytes(nchunk) = (106832 + 41216*nchunk)*4 : n=32 -> 5.7MB, 64 -> 11.0MB, 128 -> 21.5MB

// ============ K1: symmetric Gram partials (split-K) + column-sum partials ============
// 10 upper-triangle 64x64 tiles; grid = 10*nchunk; prefetched double-buffer staging.
__global__ __launch_bounds__(256) void k1_gram(const float* __restrict__ F,
                                               float* __restrict__ ws,
                                               int nchunk, int rpc) {
    const int TI[10] = {0,0,0,0,1,1,1,2,2,3};
    const int TJ[10] = {0,1,2,3,1,2,3,2,3,3};
    const int t     = blockIdx.x % 10;
    const int chunk = blockIdx.x / 10;
    const int i0 = TI[t] * 64, j0 = TJ[t] * 64;
    const bool diag = (TI[t] == TJ[t]);
    const int r0 = chunk * rpc;
    const int tid = threadIdx.x;

    __shared__ __align__(16) float Alds[32][64];
    __shared__ __align__(16) float Blds[32][64];

    float acc[4][4] = {};
    float colacc = 0.f;
    const int tm = tid & 15, tn = tid >> 4;   // 4x4 micro-tile
    const int kk0 = tid >> 4, sg = tid & 15;  // staging coords (32 rows x 16 float4 segs)

    float4 pa0, pa1, pb0, pb1;
    {   // preload kb = 0
        const float* ra = &F[(size_t)r0 * IN_F];
        pa0 = *(const float4*)&ra[(size_t)(kk0)      * IN_F + i0 + sg * 4];
        pa1 = *(const float4*)&ra[(size_t)(kk0 + 16) * IN_F + i0 + sg * 4];
        pb0 = *(const float4*)&ra[(size_t)(kk0)      * IN_F + j0 + sg * 4];
        pb1 = *(const float4*)&ra[(size_t)(kk0 + 16) * IN_F + j0 + sg * 4];
    }
    for (int kb = 0; kb < rpc; kb += 32) {
        __syncthreads();
        *(float4*)&Alds[kk0][sg * 4]      = pa0;
        *(float4*)&Alds[kk0 + 16][sg * 4] = pa1;
        *(float4*)&Blds[kk0][sg * 4]      = pb0;
        *(float4*)&Blds[kk0 + 16][sg * 4] = pb1;
        __syncthreads();
        if (kb + 32 < rpc) {   // prefetch next slab while computing this one
            const float* ra = &F[(size_t)(r0 + kb + 32) * IN_F];
            pa0 = *(const float4*)&ra[(size_t)(kk0)      * IN_F + i0 + sg * 4];
            pa1 = *(const float4*)&ra[(size_t)(kk0 + 16) * IN_F + i0 + sg * 4];
            pb0 = *(const float4*)&ra[(size_t)(kk0)      * IN_F + j0 + sg * 4];
            pb1 = *(const float4*)&ra[(size_t)(kk0 + 16) * IN_F + j0 + sg * 4];
        }
#pragma unroll 8
        for (int kk = 0; kk < 32; kk++) {
            float4 av = *(const float4*)&Alds[kk][tm * 4];
            float4 bv = *(const float4*)&Blds[kk][tn * 4];
            float a_[4] = {av.x, av.y, av.z, av.w};
            float b_[4] = {bv.x, bv.y, bv.z, bv.w};
#pragma unroll
            for (int i = 0; i < 4; i++)
#pragma unroll
                for (int j = 0; j < 4; j++) acc[i][j] += a_[i] * b_[j];
        }
        if (diag && tid < 64) {
#pragma unroll 8
            for (int kk = 0; kk < 32; kk++) colacc += Alds[kk][tid];
        }
    }
    float* Gp = ws + OFF_GP + (size_t)(t * nchunk + chunk) * 4096;
#pragma unroll
    for (int i = 0; i < 4; i++)
#pragma unroll
        for (int j = 0; j < 4; j++)
            Gp[(tm * 4 + i) * 64 + tn * 4 + j] = acc[i][j];
    if (diag && tid < 64)
        ws[OFF_GP + 40960u * (size_t)nchunk + (size_t)chunk * 256 + i0 + tid] = colacc;
}

// ============ K2a: reduce partials -> G (symmetric reconstruct), colsums -> fbar ============
__global__ __launch_bounds__(256) void k2a_reduce(float* __restrict__ ws, int nchunk) {
    const int tid = threadIdx.x;
    const int e = blockIdx.x * 256 + tid;      // 0..65535
    int a = e >> 8, b = e & 255;
    int i = a >> 6, j = b >> 6, x = a & 63, y = b & 63;
    if (i > j) { int s1 = i; i = j; j = s1; int s2 = x; x = y; y = s2; }
    const int t = i * (7 - i) / 2 + j;
    const float* Gp = ws + OFF_GP + (size_t)t * nchunk * 4096;
    float s = 0.f;
    for (int c = 0; c < nchunk; c++) s += Gp[(size_t)c * 4096 + x * 64 + y];
    ws[OFF_G + e] = s;
    if (blockIdx.x == 0) {
        const float* CS = ws + OFF_GP + 40960u * (size_t)nchunk;
        float fs = 0.f;
        for (int c = 0; c < nchunk; c++) fs += CS[c * 256 + tid];
        ws[OFF_FBAR + tid] = fs * (1.0f / N_PTS);
        int* wi = (int*)(ws + OFF_INT);
        if (tid < 16) wi[IO_COUNTS + tid] = 0;
    }
}

// ============ K2b: per-column mu/var -> scale/shift ============
__global__ __launch_bounds__(256) void k2b_stats(const float* __restrict__ W1,
                                                 const float* __restrict__ gamma,
                                                 const float* __restrict__ beta,
                                                 float* __restrict__ ws) {
    const int tid = threadIdx.x;
    const int j0 = blockIdx.x * 16;
    __shared__ __align__(16) float wl[16][256];
    __shared__ float pw[16][8];
#pragma unroll
    for (int q = 0; q < 4; q++) {
        float4 v = *(const float4*)&W1[(size_t)tid * CF + j0 + q * 4];
        wl[q * 4 + 0][tid] = v.x; wl[q * 4 + 1][tid] = v.y;
        wl[q * 4 + 2][tid] = v.z; wl[q * 4 + 3][tid] = v.w;
    }
    __syncthreads();
    float acc[16];
#pragma unroll
    for (int jj = 0; jj < 16; jj++) acc[jj] = 0.f;
    const float* G = ws + OFF_G;
    for (int b = 0; b < 256; b++) {           // s_a = sum_b G[b][a] * w[jj][b]
        float g = G[b * 256 + tid];
#pragma unroll
        for (int jj = 0; jj < 16; jj++) acc[jj] += g * wl[jj][b];
    }
    float fb = ws[OFF_FBAR + tid];
    const int lane = tid & 63, wave = tid >> 6;
#pragma unroll
    for (int jj = 0; jj < 16; jj++) {
        float w = wl[jj][tid];
        float v = w * acc[jj];                // -> w^T G w
        float m = fb * w;                     // -> mu = fbar . w
#pragma unroll
        for (int off = 32; off >= 1; off >>= 1) {
            v += __shfl_xor(v, off);
            m += __shfl_xor(m, off);
        }
        if (lane == 0) { pw[jj][wave * 2] = v; pw[jj][wave * 2 + 1] = m; }
    }
    __syncthreads();
    if (tid < 16) {
        int jj = tid;
        float v = 0.f, m = 0.f;
        for (int w2 = 0; w2 < 4; w2++) { v += pw[jj][w2 * 2]; m += pw[jj][w2 * 2 + 1]; }
        float mu  = m;
        float var = v * (1.0f / N_PTS) - mu * mu;
        float sc  = gamma[j0 + jj] * rsqrtf(var + BN_EPS);
        float sh  = beta[j0 + jj] - mu * sc;
        ws[OFF_SCALE + j0 + jj] = sc;
        ws[OFF_SHIFT + j0 + jj] = sh;
    }
}

// ============ K3: category histogram ============
__global__ __launch_bounds__(256) void k3_hist(const int* __restrict__ cats,
                                               float* __restrict__ ws) {
    __shared__ int h[16];
    int tid = threadIdx.x;
    if (tid < 16) h[tid] = 0;
    __syncthreads();
    for (int n = blockIdx.x * 256 + tid; n < N_PTS; n += 64 * 256)
        atomicAdd(&h[cats[n]], 1);
    __syncthreads();
    int* wi = (int*)(ws + OFF_INT);
    if (tid < 16) atomicAdd(&wi[IO_COUNTS + tid], h[tid]);
}

// ============ K4: prefix sums (serial, tiny) ============
__global__ void k4_prefix(float* __restrict__ ws) {
    int* wi = (int*)(ws + OFF_INT);
    if (threadIdx.x == 0) {
        int co = 0, ts = 0;
        wi[IO_CATOFF] = 0; wi[IO_TILEST] = 0;
        for (int c = 0; c < 16; c++) {
            int cnt = wi[IO_COUNTS + c];
            wi[IO_CURSOR + c] = co;
            co += cnt; ts += (cnt + 63) >> 6;
            wi[IO_CATOFF + c + 1] = co;
            wi[IO_TILEST + c + 1] = ts;
        }
        wi[IO_NTILES] = ts;
    }
}

// ============ K4b: scatter point ids grouped by category ============
__global__ __launch_bounds__(256) void k4b_scatter(const int* __restrict__ cats,
                                                   float* __restrict__ ws) {
    int* wi = (int*)(ws + OFF_INT);
    for (int n = blockIdx.x * 256 + threadIdx.x; n < N_PTS; n += 64 * 256) {
        int c = cats[n];
        int idx = atomicAdd(&wi[IO_CURSOR + c], 1);
        wi[IO_ORDER + idx] = n;
    }
}

// ============ K5: per-category GEMM + BN + LeakyReLU + Wc + log_softmax + scatter ============
__global__ __launch_bounds__(256) void k5_main(const float* __restrict__ F,
                                               const float* __restrict__ W1,
                                               const float* __restrict__ Wc,
                                               const float* __restrict__ bias,
                                               const int* __restrict__ shifts,
                                               const int* __restrict__ seg_lens,
                                               const float* __restrict__ ws,
                                               float* __restrict__ out) {
    const int* wi = (const int*)(ws + OFF_INT);
    const int t = blockIdx.x;
    if (t >= wi[IO_NTILES]) return;
    int c = 0;
    while (!(t >= wi[IO_TILEST + c] && t < wi[IO_TILEST + c + 1])) c++;
    const int lt = t - wi[IO_TILEST + c];
    const int base = wi[IO_CATOFF + c] + lt * 64;
    const int npts = min(64, wi[IO_COUNTS + c] - lt * 64);
    const int tid = threadIdx.x;

    __shared__ __align__(16) float Wlds[32][256];   // reused as red[16][64][6] in epilogue
    __shared__ __align__(16) float Flds[32][65];
    __shared__ float scl[256], shl[256];
    __shared__ float wcl[256 * 6];
    __shared__ int plds[64];

    if (tid < 64) plds[tid] = wi[IO_ORDER + base + min(tid, npts - 1)];
    scl[tid] = ws[OFF_SCALE + c * 256 + tid];
    shl[tid] = ws[OFF_SHIFT + c * 256 + tid];
#pragma unroll
    for (int i = 0; i < 6; i++) wcl[tid + i * 256] = Wc[(size_t)c * 1536 + tid + i * 256];
    __syncthreads();

    const int tm = tid & 15, tn = tid >> 4;   // 4 pts x 16 cols per thread
    const int fm = tid >> 2, fsg = tid & 3;   // F staging coords
    float acc[4][16] = {};

    float4 pw[8], pf0, pf1;
    {   // preload k0 = 0
        const float* fsrc = &F[(size_t)plds[fm] * IN_F + fsg * 8];
        pf0 = *(const float4*)fsrc;
        pf1 = *(const float4*)(fsrc + 4);
#pragma unroll
        for (int i2 = 0; i2 < 8; i2++) {
            int slot = i2 * 256 + tid, kk = slot >> 6, sg = slot & 63;
            pw[i2] = *(const float4*)&W1[(size_t)kk * CF + c * 256 + sg * 4];
        }
    }
    for (int k0 = 0; k0 < 256; k0 += 32) {
        __syncthreads();
        Flds[fsg * 8 + 0][fm] = pf0.x; Flds[fsg * 8 + 1][fm] = pf0.y;
        Flds[fsg * 8 + 2][fm] = pf0.z; Flds[fsg * 8 + 3][fm] = pf0.w;
        Flds[fsg * 8 + 4][fm] = pf1.x; Flds[fsg * 8 + 5][fm] = pf1.y;
        Flds[fsg * 8 + 6][fm] = pf1.z; Flds[fsg * 8 + 7][fm] = pf1.w;
#pragma unroll
        for (int i2 = 0; i2 < 8; i2++) {
            int slot = i2 * 256 + tid, kk = slot >> 6, sg = slot & 63;
            *(float4*)&Wlds[kk][sg * 4] = pw[i2];
        }
        __syncthreads();
        if (k0 + 32 < 256) {   // prefetch next K-slab under compute
            const float* fsrc = &F[(size_t)plds[fm] * IN_F + (k0 + 32) + fsg * 8];
            pf0 = *(const float4*)fsrc;
            pf1 = *(const float4*)(fsrc + 4);
#pragma unroll
            for (int i2 = 0; i2 < 8; i2++) {
                int slot = i2 * 256 + tid, kk = slot >> 6, sg = slot & 63;
                pw[i2] = *(const float4*)&W1[(size_t)(k0 + 32 + kk) * CF + c * 256 + sg * 4];
            }
        }
#pragma unroll 4
        for (int kk = 0; kk < 32; kk++) {
            float4 f4 = *(const float4*)&Flds[kk][tm * 4];
            float f_[4] = {f4.x, f4.y, f4.z, f4.w};
#pragma unroll
            for (int q = 0; q < 4; q++) {
                float4 w4 = *(const float4*)&Wlds[kk][tn * 16 + q * 4];
                float w_[4] = {w4.x, w4.y, w4.z, w4.w};
#pragma unroll
                for (int i = 0; i < 4; i++)
#pragma unroll
                    for (int u = 0; u < 4; u++)
                        acc[i][q * 4 + u] += f_[i] * w_[u];
            }
        }
    }

    // epilogue: BN + LeakyReLU + partial logits vs Wc
    float pl[4][6];
#pragma unroll
    for (int i = 0; i < 4; i++)
#pragma unroll
        for (int s = 0; s < 6; s++) pl[i][s] = 0.f;
#pragma unroll
    for (int j = 0; j < 16; j++) {
        int n = tn * 16 + j;
        float sc = scl[n], sh = shl[n];
#pragma unroll
        for (int i = 0; i < 4; i++) {
            float x = acc[i][j] * sc + sh;
            x = (x >= 0.f) ? x : 0.2f * x;
#pragma unroll
            for (int s = 0; s < 6; s++) pl[i][s] += x * wcl[n * 6 + s];
        }
    }
    __syncthreads();                          // Wlds now free for reuse
    float* red = &Wlds[0][0];                 // 16*64*6 = 6144 floats, fits in 8192
#pragma unroll
    for (int i = 0; i < 4; i++)
#pragma unroll
        for (int s = 0; s < 6; s++)
            red[(tn * 64 + tm * 4 + i) * 6 + s] = pl[i][s];
    __syncthreads();

    if (tid < 64 && tid < npts) {
        const int m = tid;
        float lg[6];
#pragma unroll
        for (int s = 0; s < 6; s++) lg[s] = bias[s];
        for (int w = 0; w < 16; w++)
#pragma unroll
            for (int s = 0; s < 6; s++) lg[s] += red[(w * 64 + m) * 6 + s];
        float mx = lg[0];
#pragma unroll
        for (int s = 1; s < 6; s++) mx = fmaxf(mx, lg[s]);
        float se = 0.f;
#pragma unroll
        for (int s = 0; s < 6; s++) se += expf(lg[s] - mx);
        float lse = mx + logf(se);
        const int pid = plds[m];
        const int sh = shifts[c], ln = seg_lens[c];
        float* orow = out + (size_t)pid * OUTK;
        for (int k = 0; k < OUTK; k++) {
            int j = k - sh;
            orow[k] = (j >= 0 && j < ln) ? (lg[j] - lse) : 0.f;
        }
    }
}

extern "C" void kernel_launch(void* const* d_in, const int* in_sizes, int n_in,
                              void* d_out, int out_size, void* d_ws, size_t ws_size,
                              hipStream_t stream) {
    const float* F      = (const float*)d_in[0];
    const float* W1     = (const float*)d_in[1];
    const float* gamma  = (const float*)d_in[2];
    const float* beta   = (const float*)d_in[3];
    const float* Wc     = (const float*)d_in[4];
    const float* bias   = (const float*)d_in[5];
    const int*  cats    = (const int*)d_in[6];
    const int*  shifts  = (const int*)d_in[7];
    const int*  seglens = (const int*)d_in[8];
    float* out = (float*)d_out;
    float* ws  = (float*)d_ws;

    // pick largest K-split that fits ws: bytes(n) = (OFF_GP + 41216*n)*4
    int nchunk = 32;
    if (ws_size >= ((size_t)OFF_GP + 41216ull * 128) * 4) nchunk = 128;
    else if (ws_size >= ((size_t)OFF_GP + 41216ull * 64) * 4) nchunk = 64;
    const int rpc = N_PTS / nchunk;

    hipLaunchKernelGGL(k1_gram,     dim3(10 * nchunk), dim3(256), 0, stream, F, ws, nchunk, rpc);
    hipLaunchKernelGGL(k2a_reduce,  dim3(256), dim3(256), 0, stream, ws, nchunk);
    hipLaunchKernelGGL(k2b_stats,   dim3(256), dim3(256), 0, stream, W1, gamma, beta, ws);
    hipLaunchKernelGGL(k3_hist,     dim3(64),  dim3(256), 0, stream, cats, ws);
    hipLaunchKernelGGL(k4_prefix,   dim3(1),   dim3(64),  0, stream, ws);
    hipLaunchKernelGGL(k4b_scatter, dim3(64),  dim3(256), 0, stream, cats, ws);
    hipLaunchKernelGGL(k5_main,     dim3(528), dim3(256), 0, stream,
                       F, W1, Wc, bias, shifts, seglens, ws, out);
}